// Round 1
// baseline (970.833 us; speedup 1.0000x reference)
//
#include <hip/hip_runtime.h>
#include <math.h>

#define NSPH 7
#define NRAD 6
#define NC 42       // NSPH*NRAD
#define RSTRIDE 44  // padded row stride: 44 floats = 176 B, 16B-aligned rows

// Zeros of spherical Bessel j_l, l=0..6, first 6 each (fp64, ~1e-9 accurate).
__constant__ double ZD[NC] = {
  // l=0: k*pi
  3.141592653589793, 6.283185307179586, 9.424777960769380, 12.566370614359172, 15.707963267948966, 18.849555921538759,
  // l=1
  4.493409457909064, 7.725251836937707, 10.904121659428899, 14.066193912831473, 17.220755271930768, 20.371302959287563,
  // l=2
  5.763459196894550, 9.095011330476355, 12.322940970566582, 15.514603010886749, 18.689036355362822, 21.853874222709767,
  // l=3
  6.987932000500519, 10.417118547379365, 13.698023153250246, 16.923621285214318, 20.121806174454748, 23.304246988939651,
  // l=4
  8.182561452571243, 11.704907154570317, 15.039664707616530, 18.301255959541888, 21.525417733399979, 24.727565547835114,
  // l=5
  9.355812111042747, 12.966530172775334, 16.354709638669827, 19.653152101821304, 22.904550647902713, 26.127750137384344,
  // l=6
  10.512835408094290, 14.207392458842460, 17.647974902806614, 20.983463068944362, 24.262768008042153, 27.507868390660500,
};

// NORMS computed in fp64 on device: sqrt(2)/|j_{l+1}(zero)| — stable here
// (z >= pi, order <= 7 => amplification ~50x, fp64 => exact at fp32).
__global__ void norms_kernel(float* __restrict__ norms) {
  int c = threadIdx.x;
  if (c >= NC) return;
  int l = c / NRAD;
  double z = ZD[c];
  double s = sin(z), co = cos(z);
  double jm = s / z;                 // j0
  double jc = s / (z * z) - co / z;  // j1
  for (int i = 1; i <= l; ++i) {     // after loop: jc = j_{l+1}
    double jn = (2.0 * i + 1.0) / z * jc - jm;
    jm = jc; jc = jn;
  }
  norms[c] = (float)(sqrt(2.0) / fabs(jc));
}

// rbf table: one thread per (e, c) with c in [0,44); c>=42 are pad lanes.
// fp32 recurrence mirrors the reference op-for-op. Precise sincosf is
// REQUIRED: upward recurrence amplifies seed error ~7e3x at l=6, z~1.05.
__global__ __launch_bounds__(256) void rbf_kernel(const float* __restrict__ dist,
                                                  const float* __restrict__ norms,
                                                  float* __restrict__ rbf, int E) {
  int tid = blockIdx.x * 256 + threadIdx.x;
  int e = tid / RSTRIDE;
  int c = tid - e * RSTRIDE;
  if (e >= E || c >= NC) return;
  int l = c / NRAD;
  float x = dist[e] / 5.0f;          // CUTOFF=5, IEEE div to match ref
  float z = x * (float)ZD[c];
  float s, co;
  sincosf(z, &s, &co);
  float j0 = s / z;
  float res;
  if (l == 0) {
    res = j0;
  } else {
    float jm = j0;
    float jc = s / (z * z) - co / z; // j1
    for (int i = 1; i < l; ++i) {
      float jn = (float)(2 * i + 1) / z * jc - jm;
      jm = jc; jc = jn;
    }
    res = jc;
  }
  rbf[(size_t)e * RSTRIDE + c] = norms[c] * res;
}

// Wave-cooperative gather. Phase 1: each lane computes the 7 cbf values and
// idx for its own t, stashes them in a tiny LDS table (stride 7 -> 2 lanes
// per bank on the write = free; reads are broadcast/conflict-free).
// Phase 2: each wave is 3 groups of 21 lanes; a group reads one FULL rbf row
// as 21 contiguous float2 chunks in ONE load instruction (~7 cache lines for
// 3 random rows vs 64 lines/instr in the per-lane-row layout), multiplies by
// the single cbf value each chunk needs (c=2j,2j+1 never straddles an l
// boundary since l boundaries are even), and stores float2 directly to out
// (3 consecutive rows = 504 B dense per instruction; 8-B alignment holds:
// t*168 % 8 == 0). No 43-KB staging buffer -> LDS 8.2 KB -> occupancy is
// register-limited (~2.5x more waves to hide L3 gather latency).
__global__ __launch_bounds__(256) void gather_kernel(const float* __restrict__ angle,
                                                     const int* __restrict__ idx_kj,
                                                     const float* __restrict__ rbf,
                                                     float* __restrict__ out, int T) {
  __shared__ float cb_lds[256 * NSPH]; // stride 7
  __shared__ int   idx_lds[256];
  const int tid = threadIdx.x;
  const long long t = (long long)blockIdx.x * 256 + tid;

  if (t < (long long)T) {
    float ct = cosf(angle[t]);
    float* cw = &cb_lds[tid * NSPH];
    // cbf[l] = sqrt((2l+1)/(4pi)) * P_l(ct), Legendre recurrence (stable)
    cw[0] = 0.28209479177387814f;
    cw[1] = 0.4886025119029199f * ct;
    float pm = 1.0f, pc = ct, pn;
    pn = (3.0f * ct * pc - 1.0f * pm) / 2.0f; cw[2] = 0.6307831305050401f * pn; pm = pc; pc = pn;
    pn = (5.0f * ct * pc - 2.0f * pm) / 3.0f; cw[3] = 0.7463526651802308f * pn; pm = pc; pc = pn;
    pn = (7.0f * ct * pc - 3.0f * pm) / 4.0f; cw[4] = 0.8462843753216345f * pn; pm = pc; pc = pn;
    pn = (9.0f * ct * pc - 4.0f * pm) / 5.0f; cw[5] = 0.9356025796273889f * pn; pm = pc; pc = pn;
    pn = (11.0f * ct * pc - 5.0f * pm) / 6.0f; cw[6] = 1.0171072362820548f * pn;
    idx_lds[tid] = idx_kj[t];
  }
  __syncthreads();

  const int wave = tid >> 6;
  const int lane = tid & 63;
  const int g = lane / 21;         // 0..2 workers, lane 63 -> 3 (idle)
  const int j = lane - g * 21;     // chunk index 0..20 within the row
  if (g >= 3) return;
  const int myl = j / 3;           // fixed Legendre index for this lane's chunk
  const long long waveT0 = (long long)blockIdx.x * 256 + (long long)wave * 64;

  #pragma unroll
  for (int i = 0; i < 22; ++i) {
    const int r = 3 * i + g;       // row-in-wave handled by this group
    const long long tt = waveT0 + r;
    if (r < 64 && tt < (long long)T) {
      const int tloc = wave * 64 + r;
      const int row = idx_lds[tloc];                       // broadcast read
      const float m = cb_lds[tloc * NSPH + myl];           // 7 banks, bcast x3
      const float2 v = *(const float2*)(rbf + (size_t)row * RSTRIDE + 2 * j);
      float2 o; o.x = v.x * m; o.y = v.y * m;
      *(float2*)(out + (size_t)tt * NC + 2 * j) = o;
    }
  }
}

extern "C" void kernel_launch(void* const* d_in, const int* in_sizes, int n_in,
                              void* d_out, int out_size, void* d_ws, size_t ws_size,
                              hipStream_t stream) {
  const float* dist   = (const float*)d_in[0];
  const float* angle  = (const float*)d_in[1];
  const int*   idx_kj = (const int*)d_in[2];
  float* out = (float*)d_out;
  const int E = in_sizes[0];
  const int T = in_sizes[1];

  // ws layout: [0,64) floats: norms (42 used); rbf table at +64 floats
  // (256 B, keeps 16B row alignment). Needs 256 + E*44*4 bytes (~88 MB).
  float* norms = (float*)d_ws;
  float* rbf   = (float*)d_ws + 64;

  hipLaunchKernelGGL(norms_kernel, dim3(1), dim3(64), 0, stream, norms);

  const long long tot1 = (long long)E * RSTRIDE;
  const int g1 = (int)((tot1 + 255) / 256);
  hipLaunchKernelGGL(rbf_kernel, dim3(g1), dim3(256), 0, stream, dist, norms, rbf, E);

  const int g2 = (int)(((long long)T + 255) / 256);
  hipLaunchKernelGGL(gather_kernel, dim3(g2), dim3(256), 0, stream, angle, idx_kj, rbf, out, T);
}